// Round 4
// baseline (401.874 us; speedup 1.0000x reference)
//
#include <hip/hip_runtime.h>
#include <hip/hip_bf16.h>
#include <math.h>

#define B_ 16
#define S_ 1024
#define D_ 256
#define H_ 8
#define L_ 4
#define DH_ 32
#define OBS_ 160
#define ACT_ 96
#define M_ (B_*S_)   // 16384

typedef __attribute__((ext_vector_type(8)))  short short8v;   // 8 bf16
typedef __attribute__((ext_vector_type(4)))  short short4v;   // 4 bf16
typedef __attribute__((ext_vector_type(4)))  float f32x4;
typedef __attribute__((ext_vector_type(16))) float f32x16;
typedef __attribute__((ext_vector_type(4)))  unsigned uint4v;

#define ALPHA_ 0.25507313f   // log2(e)/sqrt(32)

__device__ inline short bf16rne(float x) {
    unsigned u = __builtin_bit_cast(unsigned, x);
    unsigned r = (u + 0x7fffu + ((u >> 16) & 1u)) >> 16;
    return (short)r;
}

#if __has_builtin(__builtin_amdgcn_exp2f)
#define EXP2F(x) __builtin_amdgcn_exp2f(x)
#else
#define EXP2F(x) exp2f(x)
#endif

__device__ inline unsigned cvtpk_bf16(float lo, float hi) {
    unsigned r;
    asm("v_cvt_pk_bf16_f32 %0, %1, %2" : "=v"(r) : "v"(lo), "v"(hi));
    return r;
}

// HW half-wave swap: dst' = {src.hi32lanes, dst.hi32lanes},
//                    src' = {src.lo32lanes, dst.lo32lanes}
__device__ inline void pswap(unsigned& dst, unsigned& src) {
    asm("v_permlane32_swap_b32 %0, %1" : "+v"(dst), "+v"(src));
}

// ------------------------------------------------------------ RoPE table
// [i=0..15][s=0..1023] so epilogues vector-load cos/sin along 4 consecutive s.
__global__ __launch_bounds__(256) void rope_table_k(float* __restrict__ cosT2,
                                                    float* __restrict__ sinT2) {
    int idx = blockIdx.x * 256 + threadIdx.x;   // 16384
    int i = idx >> 10, s = idx & 1023;
    float invf = powf(10000.0f, -(float)(2 * i) / 32.0f);
    float ang = (float)s * invf;
    float sn, cs;
    sincosf(ang, &sn, &cs);
    cosT2[idx] = cs;
    sinT2[idx] = sn;
}

// ------------------------------------------------------------ input concat+cvt
__global__ __launch_bounds__(256) void cvt_in_k(const float* __restrict__ obs,
                                                const float* __restrict__ act,
                                                short* __restrict__ xIn) {
    const int idx = (blockIdx.x * 256 + threadIdx.x) * 8;
    const int row = idx >> 8, col = idx & 255;
    const float* s = (col < OBS_) ? (obs + (size_t)row * OBS_ + col)
                                  : (act + (size_t)row * ACT_ + (col - OBS_));
    const float4 v0 = *(const float4*)s;
    const float4 v1 = *(const float4*)(s + 4);
    short8v o = {bf16rne(v0.x), bf16rne(v0.y), bf16rne(v0.z), bf16rne(v0.w),
                 bf16rne(v1.x), bf16rne(v1.y), bf16rne(v1.z), bf16rne(v1.w)};
    *(short8v*)&xIn[idx] = o;
}

// ------------------------------------------------------------ weight cvt+transpose
__global__ __launch_bounds__(256) void wconv_k(
    const float* __restrict__ qW, const float* __restrict__ kW,
    const float* __restrict__ vW, const float* __restrict__ oW,
    const float* __restrict__ outW, const float* __restrict__ inW,
    short* __restrict__ WTqkv, short* __restrict__ WTo,
    short* __restrict__ WTf, short* __restrict__ WTin)
{
    __shared__ float T[64][65];
    const int z = blockIdx.y;           // 0..17
    const int bx = blockIdx.x;          // 0..15
    const int tr = (bx & 3) * 64, tc = (bx >> 2) * 64;
    const float* src;
    short* dst;
    if (z < 16) {
        int lay = z >> 2, w = z & 3;
        if (w == 0)      { src = qW + lay * 65536; dst = WTqkv + lay * 196608; }
        else if (w == 1) { src = kW + lay * 65536; dst = WTqkv + lay * 196608 + 65536; }
        else if (w == 2) { src = vW + lay * 65536; dst = WTqkv + lay * 196608 + 131072; }
        else             { src = oW + lay * 65536; dst = WTo + lay * 65536; }
    } else if (z == 16) { src = outW; dst = WTf; }
    else                { src = inW;  dst = WTin; }
    const int tid = threadIdx.x;
    #pragma unroll
    for (int it = 0; it < 4; ++it) {
        int r = (tid >> 4) + it * 16, c = (tid & 15) * 4;
        *(float4*)&T[r][c] = *(const float4*)&src[(size_t)(tr + r) * 256 + tc + c];
    }
    __syncthreads();
    #pragma unroll
    for (int it = 0; it < 4; ++it) {
        int n = (tid >> 4) + it * 16, k = (tid & 15) * 4;
        short4v o = {bf16rne(T[k][n]), bf16rne(T[k + 1][n]),
                     bf16rne(T[k + 2][n]), bf16rne(T[k + 3][n])};
        *(short4v*)&dst[(size_t)(tc + n) * 256 + tr + k] = o;
    }
}

// ------------------------------------------------------------ MFMA GEMM
// EPI 0: QKV fused (N=768): Q -> *ALPHA,rope -> (B,H,S,DH); K -> rope ->
//        (B,H,S,DH); V -> (B,H,DH,S). All bf16.
// EPI 1: + residual xF -> xF(f32) + xB(bf16)
// EPI 2: -> xF + xB
// EPI 3: -> yF (f32)
template<int EPI>
__global__ __launch_bounds__(256) void gemm_k(
    const short* __restrict__ A, const short* __restrict__ WT,
    const float* __restrict__ bq, const float* __restrict__ bk,
    const float* __restrict__ bv,
    float* __restrict__ xF, short* __restrict__ xB,
    short* __restrict__ Q2, short* __restrict__ K2, short* __restrict__ VT,
    float* __restrict__ yF,
    const float* __restrict__ cosT2, const float* __restrict__ sinT2)
{
    __shared__ short As[2][128 * 32];
    __shared__ short Bs[2][64 * 32];
    const int tid = threadIdx.x;
    const int l = tid & 63;
    const int wid = tid >> 6, wr = wid >> 1, wc = wid & 1;
    const int bn = blockIdx.x * 64, bm = blockIdx.y * 128;

    const short* aSrc0 = A + (size_t)(bm + (tid >> 2)) * 256 + (tid & 3) * 8;
    const short* aSrc1 = aSrc0 + 64 * 256;
    const short* bSrc  = WT + (size_t)(bn + (tid >> 2)) * 256 + (tid & 3) * 8;

    short8v a0 = *(const short8v*)aSrc0;
    short8v a1 = *(const short8v*)aSrc1;
    short8v b0 = *(const short8v*)bSrc;
    *(short8v*)&As[0][tid * 8]         = a0;
    *(short8v*)&As[0][(tid + 256) * 8] = a1;
    *(short8v*)&Bs[0][tid * 8]         = b0;
    __syncthreads();

    f32x4 acc[4][2];
    #pragma unroll
    for (int i = 0; i < 4; ++i)
        #pragma unroll
        for (int j = 0; j < 2; ++j) acc[i][j] = (f32x4){0.f, 0.f, 0.f, 0.f};

    #pragma unroll
    for (int t = 0; t < 8; ++t) {
        const int cur = t & 1;
        short8v na0, na1, nb;
        if (t < 7) {
            const int k = (t + 1) * 32;
            na0 = *(const short8v*)&aSrc0[k];
            na1 = *(const short8v*)&aSrc1[k];
            nb  = *(const short8v*)&bSrc[k];
        }
        short8v af[4], bf[2];
        #pragma unroll
        for (int i = 0; i < 4; ++i)
            af[i] = *(const short8v*)&As[cur][(wr * 64 + i * 16 + (l & 15)) * 32 + (l >> 4) * 8];
        #pragma unroll
        for (int j = 0; j < 2; ++j)
            bf[j] = *(const short8v*)&Bs[cur][(wc * 32 + j * 16 + (l & 15)) * 32 + (l >> 4) * 8];
        #pragma unroll
        for (int i = 0; i < 4; ++i)
            #pragma unroll
            for (int j = 0; j < 2; ++j)
                acc[i][j] = __builtin_amdgcn_mfma_f32_16x16x32_bf16(af[i], bf[j], acc[i][j], 0, 0, 0);
        if (t < 7) {
            const int nxt = cur ^ 1;
            *(short8v*)&As[nxt][tid * 8]         = na0;
            *(short8v*)&As[nxt][(tid + 256) * 8] = na1;
            *(short8v*)&Bs[nxt][tid * 8]         = nb;
            __syncthreads();
        }
    }

    if (EPI == 0) {
        const int region = bn >> 8;     // 0=Q 1=K 2=V (uniform per block)
        if (region == 2) {
            #pragma unroll
            for (int i = 0; i < 4; ++i) {
                const int m0 = bm + wr * 64 + i * 16 + ((l >> 4) << 2);
                const int bI = m0 >> 10, s0 = m0 & 1023;
                #pragma unroll
                for (int j = 0; j < 2; ++j) {
                    const int nl = (bn & 255) + wc * 32 + j * 16 + (l & 15);
                    const float bb = bv[nl];
                    const f32x4 v = acc[i][j];
                    const int h = nl >> 5, dhh = nl & 31;
                    short4v o = {bf16rne(v[0] + bb), bf16rne(v[1] + bb),
                                 bf16rne(v[2] + bb), bf16rne(v[3] + bb)};
                    *(short4v*)&VT[((size_t)((bI * 8 + h) * 32 + dhh) << 10) + s0] = o;
                }
            }
        } else {
            // Q/K: bias (+scale) + rope, bounce via LDS -> (B,H,S,DH)
            const float* bias = (region == 0) ? bq : bk;
            __syncthreads();
            short* scr = &As[0][0];   // 128 x 64 bf16, chunk-XOR swizzled
            #pragma unroll
            for (int i = 0; i < 4; ++i) {
                const int tl0 = wr * 64 + i * 16 + ((l >> 4) << 2);
                const int s0r = (bm + tl0) & 1023;
                #pragma unroll
                for (int j = 0; j < 2; ++j) {
                    const int ncl = wc * 32 + j * 16 + (l & 15);
                    const int nl = (bn & 255) + ncl;
                    const float bb = bias[nl];
                    f32x4 v = acc[i][j];
                    v[0] += bb; v[1] += bb; v[2] += bb; v[3] += bb;
                    if (region == 0) { v *= ALPHA_; }
                    const int ir = (nl & 31) >> 1;
                    const f32x4 cs = *(const f32x4*)&cosT2[ir * 1024 + s0r];
                    const f32x4 sn = *(const f32x4*)&sinT2[ir * 1024 + s0r];
                    f32x4 pr;
                    #pragma unroll
                    for (int c = 0; c < 4; ++c) pr[c] = __shfl_xor(v[c], 1);
                    const float sg = (nl & 1) ? 1.f : -1.f;
                    #pragma unroll
                    for (int c = 0; c < 4; ++c)
                        v[c] = v[c] * cs[c] + sg * pr[c] * sn[c];
                    #pragma unroll
                    for (int c = 0; c < 4; ++c) {
                        const int tl = tl0 + c;
                        const int pos = (((ncl >> 3) ^ (tl & 7)) << 3) | (ncl & 7);
                        scr[tl * 64 + pos] = bf16rne(v[c]);
                    }
                }
            }
            __syncthreads();
            const int r = tid >> 1, h2 = tid & 1;
            const int tok = bm + r;
            const int bI = tok >> 10, s0 = tok & 1023;
            const int hh = ((bn & 255) >> 5) + h2;
            short* dst = ((region == 0) ? Q2 : K2)
                         + ((size_t)((bI * 8 + hh) * 1024 + s0)) * 32;
            #pragma unroll
            for (int k = 0; k < 4; ++k) {
                const int pos = ((h2 * 4 + k) ^ (r & 7)) << 3;
                *(uint4*)&dst[k * 8] = *(const uint4*)&scr[r * 64 + pos];
            }
        }
    } else {
        #pragma unroll
        for (int i = 0; i < 4; ++i) {
            const int m0 = bm + wr * 64 + i * 16 + ((l >> 4) << 2);
            #pragma unroll
            for (int j = 0; j < 2; ++j) {
                const int nn = bn + wc * 32 + j * 16 + (l & 15);
                const float bb = bq[nn];
                const f32x4 v = acc[i][j];
                #pragma unroll
                for (int c = 0; c < 4; ++c) {
                    float rr = v[c] + bb;
                    const size_t off = (size_t)(m0 + c) * 256 + nn;
                    if (EPI == 1) rr += xF[off];
                    if (EPI == 3) {
                        yF[off] = rr;
                    } else {
                        xF[off] = rr;
                        xB[off] = bf16rne(rr);
                    }
                }
            }
        }
    }
}

// ------------------------------------------------------------ Attention
// Q2/K2: bf16 (B,H,S,DH) (Q pre-scaled by log2e/sqrt(DH), both rope'd)
// VT:    bf16 (B,H,DH,S);  O: bf16 (B,S,D)
// No LDS, no barriers: all fragments are direct 16B global loads (L1/L2-fed,
// head pinned per-XCD). No running max (shift-invariant softmax, small scores).
__global__ __launch_bounds__(256) void attn_k(
    const short* __restrict__ Q2, const short* __restrict__ K2,
    const short* __restrict__ VT, short* __restrict__ O)
{
    const int tid = threadIdx.x;
    const int l = tid & 63, wid = tid >> 6;
    const int head = blockIdx.x & 127;          // b*8+h; bid%8==head%8 -> XCD-pinned
    const int qt = blockIdx.x >> 7;             // 0..7
    const int q0 = qt * 128 + wid * 32;
    const int lq = l & 31, hi = l >> 5;

    const short* Qp = Q2 + ((size_t)(head * S_ + q0 + lq)) * DH_ + hi * 8;
    const short8v Qf0 = *(const short8v*)Qp;
    const short8v Qf1 = *(const short8v*)(Qp + 16);

    const short* kp = K2 + ((size_t)(head * S_ + lq)) * DH_ + hi * 8;
    const short* vp = VT + ((size_t)(head * DH_ + lq)) * S_ + hi * 8;

    f32x16 acc = {0.f,0.f,0.f,0.f,0.f,0.f,0.f,0.f,0.f,0.f,0.f,0.f,0.f,0.f,0.f,0.f};
    float lsum = 0.f;

    short8v cK0 = *(const short8v*)kp;
    short8v cK1 = *(const short8v*)(kp + 16);
    short8v cV0 = *(const short8v*)vp;
    short8v cV1 = *(const short8v*)(vp + 16);

    for (int t = 0; t < 32; ++t) {
        short8v nK0, nK1, nV0, nV1;
        if (t < 31) {                            // prefetch next tile
            kp += 32 * DH_;
            vp += 32;
            nK0 = *(const short8v*)kp;
            nK1 = *(const short8v*)(kp + 16);
            nV0 = *(const short8v*)vp;
            nV1 = *(const short8v*)(vp + 16);
        }

        f32x16 s = {0.f,0.f,0.f,0.f,0.f,0.f,0.f,0.f,0.f,0.f,0.f,0.f,0.f,0.f,0.f,0.f};
        s = __builtin_amdgcn_mfma_f32_32x32x16_bf16(cK0, Qf0, s, 0, 0, 0);
        s = __builtin_amdgcn_mfma_f32_32x32x16_bf16(cK1, Qf1, s, 0, 0, 0);

        float p[16];
        #pragma unroll
        for (int r = 0; r < 16; ++r) p[r] = EXP2F(s[r]);
        lsum += ((((p[0] + p[1]) + (p[2] + p[3])) + ((p[4] + p[5]) + (p[6] + p[7])))
               + (((p[8] + p[9]) + (p[10] + p[11])) + ((p[12] + p[13]) + (p[14] + p[15]))));

        unsigned u0 = cvtpk_bf16(p[0],  p[1]),  u1 = cvtpk_bf16(p[2],  p[3]);
        unsigned u2 = cvtpk_bf16(p[4],  p[5]),  u3 = cvtpk_bf16(p[6],  p[7]);
        unsigned u4 = cvtpk_bf16(p[8],  p[9]),  u5 = cvtpk_bf16(p[10], p[11]);
        unsigned u6 = cvtpk_bf16(p[12], p[13]), u7 = cvtpk_bf16(p[14], p[15]);
        pswap(u2, u0);   // u0 -> P keys(0,1 | 2,3-half), u2 -> keys(4,5 | 6,7)
        pswap(u3, u1);
        pswap(u6, u4);
        pswap(u7, u5);
        uint4v P1 = {u0, u1, u2, u3};
        uint4v P2 = {u4, u5, u6, u7};

        acc = __builtin_amdgcn_mfma_f32_32x32x16_bf16(cV0, __builtin_bit_cast(short8v, P1), acc, 0, 0, 0);
        acc = __builtin_amdgcn_mfma_f32_32x32x16_bf16(cV1, __builtin_bit_cast(short8v, P2), acc, 0, 0, 0);

        if (t < 31) {
            cK0 = nK0; cK1 = nK1; cV0 = nV0; cV1 = nV1;
        }
    }

    lsum += __shfl_xor(lsum, 32);
    const float inv = 1.f / lsum;
    const int bI = head >> 3, hh = head & 7;
    const int srow = q0 + lq;
    #pragma unroll
    for (int c = 0; c < 4; ++c) {
        short4v o = {bf16rne(acc[4 * c + 0] * inv), bf16rne(acc[4 * c + 1] * inv),
                     bf16rne(acc[4 * c + 2] * inv), bf16rne(acc[4 * c + 3] * inv)};
        *(short4v*)&O[(size_t)(bI * 1024 + srow) * 256 + hh * 32 + c * 8 + hi * 4] = o;
    }
}

// ------------------------------------------------------------ LayerNorm
__global__ __launch_bounds__(256) void ln_k(
    const float* __restrict__ y, const float* __restrict__ g,
    const float* __restrict__ bta, float* __restrict__ outp)
{
    const int tid = threadIdx.x;
    const int wave = tid >> 6, lane = tid & 63;
    const int row = blockIdx.x * 4 + wave;
    const int col = lane * 4;
    float4 t = *(const float4*)&y[(size_t)row * 256 + col];
    float sum = t.x + t.y + t.z + t.w;
    float ss  = t.x * t.x + t.y * t.y + t.z * t.z + t.w * t.w;
    #pragma unroll
    for (int off = 32; off; off >>= 1) {
        sum += __shfl_xor(sum, off);
        ss  += __shfl_xor(ss, off);
    }
    float mean = sum * (1.f / 256.f);
    float var  = ss * (1.f / 256.f) - mean * mean;
    float rstd = rsqrtf(var + 1e-5f);
    float4 gv = *(const float4*)&g[col];
    float4 bv = *(const float4*)&bta[col];
    float4 o;
    o.x = (t.x - mean) * rstd * gv.x + bv.x;
    o.y = (t.y - mean) * rstd * gv.y + bv.y;
    o.z = (t.z - mean) * rstd * gv.z + bv.z;
    o.w = (t.w - mean) * rstd * gv.w + bv.w;
    float* seq = outp + B_ * D_;
    *(float4*)&seq[(size_t)row * 256 + col] = o;
    if ((row & (S_ - 1)) == S_ - 1)
        *(float4*)&outp[(size_t)(row >> 10) * 256 + col] = o;
}

// ------------------------------------------------------------ launch
extern "C" void kernel_launch(void* const* d_in, const int* in_sizes, int n_in,
                              void* d_out, int out_size, void* d_ws, size_t ws_size,
                              hipStream_t stream)
{
    const float* obs  = (const float*)d_in[0];
    const float* act  = (const float*)d_in[1];
    const float* inW  = (const float*)d_in[2];
    const float* inb  = (const float*)d_in[3];
    const float* qW   = (const float*)d_in[4];
    const float* qb   = (const float*)d_in[5];
    const float* kW   = (const float*)d_in[6];
    const float* kb   = (const float*)d_in[7];
    const float* vW   = (const float*)d_in[8];
    const float* vb   = (const float*)d_in[9];
    const float* oW   = (const float*)d_in[10];
    const float* ob   = (const float*)d_in[11];
    const float* outW = (const float*)d_in[12];
    const float* outb = (const float*)d_in[13];
    const float* lng  = (const float*)d_in[14];
    const float* lnb  = (const float*)d_in[15];
    float* outp = (float*)d_out;

    const size_t MD = (size_t)M_ * D_;
    float* xF    = (float*)d_ws;
    short* xB    = (short*)(xF + MD);
    short* xIn   = xB + MD;
    short* Q2    = xIn + MD;             // bf16 (B,H,S,DH)
    short* K2    = Q2 + MD;              // bf16 (B,H,S,DH)
    short* VT    = K2 + MD;              // bf16 (B,H,DH,S)
    short* Obf   = VT + MD;              // bf16 attn out (B,S,D)
    short* WTqkv = Obf + MD;
    short* WTo   = WTqkv + 786432;
    short* WTf   = WTo + 262144;
    short* WTin  = WTf + 65536;
    float* cosT2 = (float*)(WTin + 65536);
    float* sinT2 = cosT2 + 16384;
    float* ybuf  = (float*)Q2;           // alias: Q2/K2 dead before final GEMM

    rope_table_k<<<64, 256, 0, stream>>>(cosT2, sinT2);
    cvt_in_k<<<2048, 256, 0, stream>>>(obs, act, xIn);
    wconv_k<<<dim3(16, 18), 256, 0, stream>>>(qW, kW, vW, oW, outW, inW,
                                              WTqkv, WTo, WTf, WTin);

    gemm_k<2><<<dim3(4, 128), 256, 0, stream>>>(xIn, WTin, inb, nullptr, nullptr,
            xF, xB, nullptr, nullptr, nullptr, nullptr, nullptr, nullptr);

    for (int lay = 0; lay < L_; ++lay) {
        gemm_k<0><<<dim3(12, 128), 256, 0, stream>>>(xB, WTqkv + lay * 196608,
                qb + lay * 256, kb + lay * 256, vb + lay * 256,
                nullptr, nullptr, Q2, K2, VT, nullptr, cosT2, sinT2);
        attn_k<<<1024, 256, 0, stream>>>(Q2, K2, VT, Obf);
        gemm_k<1><<<dim3(4, 128), 256, 0, stream>>>(Obf, WTo + lay * 65536,
                ob + lay * 256, nullptr, nullptr, xF, xB,
                nullptr, nullptr, nullptr, nullptr, nullptr, nullptr);
    }

    gemm_k<3><<<dim3(4, 128), 256, 0, stream>>>(xB, WTf, outb, nullptr, nullptr,
            nullptr, nullptr, nullptr, nullptr, nullptr, ybuf, nullptr, nullptr);
    ln_k<<<M_ / 4, 256, 0, stream>>>(ybuf, lng, lnb, outp);
}

// Round 5
// 309.198 us; speedup vs baseline: 1.2997x; 1.2997x over previous
//
#include <hip/hip_runtime.h>
#include <hip/hip_bf16.h>
#include <math.h>

#define B_ 16
#define S_ 1024
#define D_ 256
#define H_ 8
#define L_ 4
#define DH_ 32
#define OBS_ 160
#define ACT_ 96
#define M_ (B_*S_)   // 16384

typedef __attribute__((ext_vector_type(8)))  short short8v;   // 8 bf16
typedef __attribute__((ext_vector_type(4)))  short short4v;   // 4 bf16
typedef __attribute__((ext_vector_type(4)))  float f32x4;
typedef __attribute__((ext_vector_type(4)))  unsigned uint4v;

#define ALPHA_ 0.25507313f   // log2(e)/sqrt(32)

__device__ inline short bf16rne(float x) {
    unsigned u = __builtin_bit_cast(unsigned, x);
    unsigned r = (u + 0x7fffu + ((u >> 16) & 1u)) >> 16;
    return (short)r;
}

#if __has_builtin(__builtin_amdgcn_exp2f)
#define EXP2F(x) __builtin_amdgcn_exp2f(x)
#else
#define EXP2F(x) exp2f(x)
#endif

__device__ inline unsigned cvtpk_bf16(float lo, float hi) {
    unsigned r;
    asm("v_cvt_pk_bf16_f32 %0, %1, %2" : "=v"(r) : "v"(lo), "v"(hi));
    return r;
}

// ------------------------------------------------------------ RoPE table
// [i=0..15][s=0..1023] so epilogues vector-load cos/sin along 4 consecutive s.
__global__ __launch_bounds__(256) void rope_table_k(float* __restrict__ cosT2,
                                                    float* __restrict__ sinT2) {
    int idx = blockIdx.x * 256 + threadIdx.x;   // 16384
    int i = idx >> 10, s = idx & 1023;
    float invf = powf(10000.0f, -(float)(2 * i) / 32.0f);
    float ang = (float)s * invf;
    float sn, cs;
    sincosf(ang, &sn, &cs);
    cosT2[idx] = cs;
    sinT2[idx] = sn;
}

// ------------------------------------------------------------ input concat+cvt
__global__ __launch_bounds__(256) void cvt_in_k(const float* __restrict__ obs,
                                                const float* __restrict__ act,
                                                short* __restrict__ xIn) {
    const int idx = (blockIdx.x * 256 + threadIdx.x) * 8;
    const int row = idx >> 8, col = idx & 255;
    const float* s = (col < OBS_) ? (obs + (size_t)row * OBS_ + col)
                                  : (act + (size_t)row * ACT_ + (col - OBS_));
    const float4 v0 = *(const float4*)s;
    const float4 v1 = *(const float4*)(s + 4);
    short8v o = {bf16rne(v0.x), bf16rne(v0.y), bf16rne(v0.z), bf16rne(v0.w),
                 bf16rne(v1.x), bf16rne(v1.y), bf16rne(v1.z), bf16rne(v1.w)};
    *(short8v*)&xIn[idx] = o;
}

// ------------------------------------------------------------ weight cvt+transpose
__global__ __launch_bounds__(256) void wconv_k(
    const float* __restrict__ qW, const float* __restrict__ kW,
    const float* __restrict__ vW, const float* __restrict__ oW,
    const float* __restrict__ outW, const float* __restrict__ inW,
    short* __restrict__ WTqkv, short* __restrict__ WTo,
    short* __restrict__ WTf, short* __restrict__ WTin)
{
    __shared__ float T[64][65];
    const int z = blockIdx.y;           // 0..17
    const int bx = blockIdx.x;          // 0..15
    const int tr = (bx & 3) * 64, tc = (bx >> 2) * 64;
    const float* src;
    short* dst;
    if (z < 16) {
        int lay = z >> 2, w = z & 3;
        if (w == 0)      { src = qW + lay * 65536; dst = WTqkv + lay * 196608; }
        else if (w == 1) { src = kW + lay * 65536; dst = WTqkv + lay * 196608 + 65536; }
        else if (w == 2) { src = vW + lay * 65536; dst = WTqkv + lay * 196608 + 131072; }
        else             { src = oW + lay * 65536; dst = WTo + lay * 65536; }
    } else if (z == 16) { src = outW; dst = WTf; }
    else                { src = inW;  dst = WTin; }
    const int tid = threadIdx.x;
    #pragma unroll
    for (int it = 0; it < 4; ++it) {
        int r = (tid >> 4) + it * 16, c = (tid & 15) * 4;
        *(float4*)&T[r][c] = *(const float4*)&src[(size_t)(tr + r) * 256 + tc + c];
    }
    __syncthreads();
    #pragma unroll
    for (int it = 0; it < 4; ++it) {
        int n = (tid >> 4) + it * 16, k = (tid & 15) * 4;
        short4v o = {bf16rne(T[k][n]), bf16rne(T[k + 1][n]),
                     bf16rne(T[k + 2][n]), bf16rne(T[k + 3][n])};
        *(short4v*)&dst[(size_t)(tc + n) * 256 + tr + k] = o;
    }
}

// ------------------------------------------------------------ MFMA GEMM
// EPI 0: QKV fused (N=768): Q -> *ALPHA,rope -> (B,H,S,DH); K -> rope ->
//        (B,H,S,DH); V -> (B,H,DH,S) with sigma-permuted key order.
// EPI 1: + residual xF -> xF(f32) + xB(bf16)
// EPI 2: -> xF + xB
// EPI 3: -> yF (f32)
template<int EPI>
__global__ __launch_bounds__(256) void gemm_k(
    const short* __restrict__ A, const short* __restrict__ WT,
    const float* __restrict__ bq, const float* __restrict__ bk,
    const float* __restrict__ bv,
    float* __restrict__ xF, short* __restrict__ xB,
    short* __restrict__ Q2, short* __restrict__ K2, short* __restrict__ VT,
    float* __restrict__ yF,
    const float* __restrict__ cosT2, const float* __restrict__ sinT2)
{
    __shared__ short As[2][128 * 32];
    __shared__ short Bs[2][64 * 32];
    const int tid = threadIdx.x;
    const int l = tid & 63;
    const int wid = tid >> 6, wr = wid >> 1, wc = wid & 1;
    const int bn = blockIdx.x * 64, bm = blockIdx.y * 128;

    const short* aSrc0 = A + (size_t)(bm + (tid >> 2)) * 256 + (tid & 3) * 8;
    const short* aSrc1 = aSrc0 + 64 * 256;
    const short* bSrc  = WT + (size_t)(bn + (tid >> 2)) * 256 + (tid & 3) * 8;

    short8v a0 = *(const short8v*)aSrc0;
    short8v a1 = *(const short8v*)aSrc1;
    short8v b0 = *(const short8v*)bSrc;
    *(short8v*)&As[0][tid * 8]         = a0;
    *(short8v*)&As[0][(tid + 256) * 8] = a1;
    *(short8v*)&Bs[0][tid * 8]         = b0;
    __syncthreads();

    f32x4 acc[4][2];
    #pragma unroll
    for (int i = 0; i < 4; ++i)
        #pragma unroll
        for (int j = 0; j < 2; ++j) acc[i][j] = (f32x4){0.f, 0.f, 0.f, 0.f};

    #pragma unroll
    for (int t = 0; t < 8; ++t) {
        const int cur = t & 1;
        short8v na0, na1, nb;
        if (t < 7) {
            const int k = (t + 1) * 32;
            na0 = *(const short8v*)&aSrc0[k];
            na1 = *(const short8v*)&aSrc1[k];
            nb  = *(const short8v*)&bSrc[k];
        }
        short8v af[4], bf[2];
        #pragma unroll
        for (int i = 0; i < 4; ++i)
            af[i] = *(const short8v*)&As[cur][(wr * 64 + i * 16 + (l & 15)) * 32 + (l >> 4) * 8];
        #pragma unroll
        for (int j = 0; j < 2; ++j)
            bf[j] = *(const short8v*)&Bs[cur][(wc * 32 + j * 16 + (l & 15)) * 32 + (l >> 4) * 8];
        #pragma unroll
        for (int i = 0; i < 4; ++i)
            #pragma unroll
            for (int j = 0; j < 2; ++j)
                acc[i][j] = __builtin_amdgcn_mfma_f32_16x16x32_bf16(af[i], bf[j], acc[i][j], 0, 0, 0);
        if (t < 7) {
            const int nxt = cur ^ 1;
            *(short8v*)&As[nxt][tid * 8]         = na0;
            *(short8v*)&As[nxt][(tid + 256) * 8] = na1;
            *(short8v*)&Bs[nxt][tid * 8]         = nb;
            __syncthreads();
        }
    }

    if (EPI == 0) {
        const int region = bn >> 8;     // 0=Q 1=K 2=V (uniform per block)
        if (region == 2) {
            #pragma unroll
            for (int i = 0; i < 4; ++i) {
                const int m0 = bm + wr * 64 + i * 16 + ((l >> 4) << 2);
                const int bI = m0 >> 10, s0 = m0 & 1023;
                // sigma key-permutation within each 32-block:
                // pos(key): key<16 -> 8*(key>>2)+(key&3); key>=16 -> that +4
                const int w  = s0 & 31;
                const int sp = (s0 & ~31) | ((((w & 15) >> 2) << 3) | ((w >> 4) << 2));
                #pragma unroll
                for (int j = 0; j < 2; ++j) {
                    const int nl = (bn & 255) + wc * 32 + j * 16 + (l & 15);
                    const float bb = bv[nl];
                    const f32x4 v = acc[i][j];
                    const int h = nl >> 5, dhh = nl & 31;
                    short4v o = {bf16rne(v[0] + bb), bf16rne(v[1] + bb),
                                 bf16rne(v[2] + bb), bf16rne(v[3] + bb)};
                    *(short4v*)&VT[((size_t)((bI * 8 + h) * 32 + dhh) << 10) + sp] = o;
                }
            }
        } else {
            // Q/K: bias (+scale) + rope, bounce via LDS -> (B,H,S,DH)
            const float* bias = (region == 0) ? bq : bk;
            __syncthreads();
            short* scr = &As[0][0];   // 128 x 64 bf16, chunk-XOR swizzled
            #pragma unroll
            for (int i = 0; i < 4; ++i) {
                const int tl0 = wr * 64 + i * 16 + ((l >> 4) << 2);
                const int s0r = (bm + tl0) & 1023;
                #pragma unroll
                for (int j = 0; j < 2; ++j) {
                    const int ncl = wc * 32 + j * 16 + (l & 15);
                    const int nl = (bn & 255) + ncl;
                    const float bb = bias[nl];
                    f32x4 v = acc[i][j];
                    v[0] += bb; v[1] += bb; v[2] += bb; v[3] += bb;
                    if (region == 0) { v *= ALPHA_; }
                    const int ir = (nl & 31) >> 1;
                    const f32x4 cs = *(const f32x4*)&cosT2[ir * 1024 + s0r];
                    const f32x4 sn = *(const f32x4*)&sinT2[ir * 1024 + s0r];
                    f32x4 pr;
                    #pragma unroll
                    for (int c = 0; c < 4; ++c) pr[c] = __shfl_xor(v[c], 1);
                    const float sg = (nl & 1) ? 1.f : -1.f;
                    #pragma unroll
                    for (int c = 0; c < 4; ++c)
                        v[c] = v[c] * cs[c] + sg * pr[c] * sn[c];
                    #pragma unroll
                    for (int c = 0; c < 4; ++c) {
                        const int tl = tl0 + c;
                        const int pos = (((ncl >> 3) ^ (tl & 7)) << 3) | (ncl & 7);
                        scr[tl * 64 + pos] = bf16rne(v[c]);
                    }
                }
            }
            __syncthreads();
            const int r = tid >> 1, h2 = tid & 1;
            const int tok = bm + r;
            const int bI = tok >> 10, s0 = tok & 1023;
            const int hh = ((bn & 255) >> 5) + h2;
            short* dst = ((region == 0) ? Q2 : K2)
                         + ((size_t)((bI * 8 + hh) * 1024 + s0)) * 32;
            #pragma unroll
            for (int k = 0; k < 4; ++k) {
                const int pos = ((h2 * 4 + k) ^ (r & 7)) << 3;
                *(uint4*)&dst[k * 8] = *(const uint4*)&scr[r * 64 + pos];
            }
        }
    } else {
        #pragma unroll
        for (int i = 0; i < 4; ++i) {
            const int m0 = bm + wr * 64 + i * 16 + ((l >> 4) << 2);
            #pragma unroll
            for (int j = 0; j < 2; ++j) {
                const int nn = bn + wc * 32 + j * 16 + (l & 15);
                const float bb = bq[nn];
                const f32x4 v = acc[i][j];
                #pragma unroll
                for (int c = 0; c < 4; ++c) {
                    float rr = v[c] + bb;
                    const size_t off = (size_t)(m0 + c) * 256 + nn;
                    if (EPI == 1) rr += xF[off];
                    if (EPI == 3) {
                        yF[off] = rr;
                    } else {
                        xF[off] = rr;
                        xB[off] = bf16rne(rr);
                    }
                }
            }
        }
    }
}

// ------------------------------------------------------------ Attention
// Q2/K2: bf16 (B,H,S,DH) (Q pre-scaled by log2e/sqrt(DH), both rope'd)
// VT:    bf16 (B,H,DH,S), key order sigma-permuted per 32-block
// O:     bf16 (B,S,D)
// Block: 1 head x 128 q (8 waves x 16 q), 16x16x32 MFMA.
// K/V tiles (32 keys) staged to LDS by waves 0-3 (reg-staged, 1 tile ahead),
// double-buffered, XOR-swizzled chunks. P needs ZERO cross-lane ops: the
// sigma permutation makes the QK C-fragment's key set == PV B-fragment's.
__global__ __launch_bounds__(512, 8) void attn_k(
    const short* __restrict__ Q2, const short* __restrict__ K2,
    const short* __restrict__ VT, short* __restrict__ O)
{
    __shared__ short LB[4096];   // [2 buf][K 32x32 | V 32x32] bf16, 8 KB
    const int tid = threadIdx.x;
    const int l = tid & 63, wid = tid >> 6;
    const int head = blockIdx.x & 127;   // b*8+h; bid%8 = head%8 -> XCD-pinned
    const int qt = blockIdx.x >> 7;      // 0..7
    const int q0w = qt * 128 + wid * 16;
    const int lq = l & 15, g = l >> 4;

    const short8v Qf = *(const short8v*)&Q2[((size_t)head * 1024 + q0w + lq) * 32 + g * 8];

    // LDS read base: row lq, chunk g, swizzle c' = c ^ ((row>>1)&3)
    const char* rbase = (const char*)LB + lq * 64 + ((g ^ ((lq >> 1) & 3)) << 4);

    // staging (threads 0..255): 0-127 stage K, 128-255 stage V
    const bool stg = (tid < 256);
    const int  sK  = (tid < 128) ? 1 : 0;
    const int  srow = (tid & 127) >> 2;
    const int  sc   = tid & 3;
    const short* gsrc = nullptr;
    int gstep = 0;
    char* wbase = nullptr;
    if (stg) {
        if (sK) { gsrc = K2 + ((size_t)head * 1024 + srow) * 32 + sc * 8; gstep = 1024; }
        else    { gsrc = VT + ((size_t)head * 32 + srow) * 1024 + sc * 8; gstep = 32; }
        wbase = (char*)LB + (sK ? 0 : 2048) + srow * 64 + ((sc ^ ((srow >> 1) & 3)) << 4);
    }

    f32x4 acc0 = {0.f, 0.f, 0.f, 0.f}, acc1 = {0.f, 0.f, 0.f, 0.f};
    const f32x4 z4 = {0.f, 0.f, 0.f, 0.f};
    float lsum = 0.f;
    short8v r = {};

    if (stg) {
        short8v r0 = *(const short8v*)gsrc; gsrc += gstep;
        r          = *(const short8v*)gsrc; gsrc += gstep;
        *(short8v*)wbase = r0;
    }
    __syncthreads();

#define ATTN_STEP(BUFOFF) do {                                                 \
        short8v Kf0 = *(const short8v*)(rbase + (BUFOFF));                     \
        short8v Kf1 = *(const short8v*)(rbase + (BUFOFF) + 1024);              \
        short8v Vf0 = *(const short8v*)(rbase + (BUFOFF) + 2048);              \
        short8v Vf1 = *(const short8v*)(rbase + (BUFOFF) + 3072);              \
        f32x4 s0 = __builtin_amdgcn_mfma_f32_16x16x32_bf16(Kf0, Qf, z4, 0,0,0);\
        f32x4 s1 = __builtin_amdgcn_mfma_f32_16x16x32_bf16(Kf1, Qf, z4, 0,0,0);\
        float p0 = EXP2F(s0[0]), p1 = EXP2F(s0[1]);                            \
        float p2 = EXP2F(s0[2]), p3 = EXP2F(s0[3]);                            \
        float p4 = EXP2F(s1[0]), p5 = EXP2F(s1[1]);                            \
        float p6 = EXP2F(s1[2]), p7 = EXP2F(s1[3]);                            \
        lsum += ((p0 + p1) + (p2 + p3)) + ((p4 + p5) + (p6 + p7));             \
        uint4v pv = {cvtpk_bf16(p0, p1), cvtpk_bf16(p2, p3),                   \
                     cvtpk_bf16(p4, p5), cvtpk_bf16(p6, p7)};                  \
        short8v Pf = __builtin_bit_cast(short8v, pv);                          \
        acc0 = __builtin_amdgcn_mfma_f32_16x16x32_bf16(Vf0, Pf, acc0, 0,0,0);  \
        acc1 = __builtin_amdgcn_mfma_f32_16x16x32_bf16(Vf1, Pf, acc1, 0,0,0);  \
    } while (0)

    #pragma unroll 1
    for (int i = 0; i < 15; ++i) {
        if (stg) { *(short8v*)(wbase + 4096) = r;
                   r = *(const short8v*)gsrc; gsrc += gstep; }
        ATTN_STEP(0);
        __syncthreads();
        if (stg) { *(short8v*)wbase = r;
                   r = *(const short8v*)gsrc; gsrc += gstep; }
        ATTN_STEP(4096);
        __syncthreads();
    }
    // t = 30
    if (stg) { *(short8v*)(wbase + 4096) = r; }
    ATTN_STEP(0);
    __syncthreads();
    // t = 31
    ATTN_STEP(4096);
#undef ATTN_STEP

    lsum += __shfl_xor(lsum, 16);
    lsum += __shfl_xor(lsum, 32);
    const float inv = 1.f / lsum;
    const int bI = head >> 3, hh = head & 7;
    short* op = O + ((size_t)(bI * 1024 + q0w + lq)) * 256 + hh * 32 + g * 4;
    short4v o0 = {bf16rne(acc0[0] * inv), bf16rne(acc0[1] * inv),
                  bf16rne(acc0[2] * inv), bf16rne(acc0[3] * inv)};
    short4v o1 = {bf16rne(acc1[0] * inv), bf16rne(acc1[1] * inv),
                  bf16rne(acc1[2] * inv), bf16rne(acc1[3] * inv)};
    *(short4v*)op = o0;
    *(short4v*)(op + 16) = o1;
}

// ------------------------------------------------------------ LayerNorm
__global__ __launch_bounds__(256) void ln_k(
    const float* __restrict__ y, const float* __restrict__ g,
    const float* __restrict__ bta, float* __restrict__ outp)
{
    const int tid = threadIdx.x;
    const int wave = tid >> 6, lane = tid & 63;
    const int row = blockIdx.x * 4 + wave;
    const int col = lane * 4;
    float4 t = *(const float4*)&y[(size_t)row * 256 + col];
    float sum = t.x + t.y + t.z + t.w;
    float ss  = t.x * t.x + t.y * t.y + t.z * t.z + t.w * t.w;
    #pragma unroll
    for (int off = 32; off; off >>= 1) {
        sum += __shfl_xor(sum, off);
        ss  += __shfl_xor(ss, off);
    }
    float mean = sum * (1.f / 256.f);
    float var  = ss * (1.f / 256.f) - mean * mean;
    float rstd = rsqrtf(var + 1e-5f);
    float4 gv = *(const float4*)&g[col];
    float4 bv = *(const float4*)&bta[col];
    float4 o;
    o.x = (t.x - mean) * rstd * gv.x + bv.x;
    o.y = (t.y - mean) * rstd * gv.y + bv.y;
    o.z = (t.z - mean) * rstd * gv.z + bv.z;
    o.w = (t.w - mean) * rstd * gv.w + bv.w;
    float* seq = outp + B_ * D_;
    *(float4*)&seq[(size_t)row * 256 + col] = o;
    if ((row & (S_ - 1)) == S_ - 1)
        *(float4*)&outp[(size_t)(row >> 10) * 256 + col] = o;
}

// ------------------------------------------------------------ launch
extern "C" void kernel_launch(void* const* d_in, const int* in_sizes, int n_in,
                              void* d_out, int out_size, void* d_ws, size_t ws_size,
                              hipStream_t stream)
{
    const float* obs  = (const float*)d_in[0];
    const float* act  = (const float*)d_in[1];
    const float* inW  = (const float*)d_in[2];
    const float* inb  = (const float*)d_in[3];
    const float* qW   = (const float*)d_in[4];
    const float* qb   = (const float*)d_in[5];
    const float* kW   = (const float*)d_in[6];
    const float* kb   = (const float*)d_in[7];
    const float* vW   = (const float*)d_in[8];
    const float* vb   = (const float*)d_in[9];
    const float* oW   = (const float*)d_in[10];
    const float* ob   = (const float*)d_in[11];
    const float* outW = (const float*)d_in[12];
    const float* outb = (const float*)d_in[13];
    const float* lng  = (const float*)d_in[14];
    const float* lnb  = (const float*)d_in[15];
    float* outp = (float*)d_out;

    const size_t MD = (size_t)M_ * D_;
    float* xF    = (float*)d_ws;
    short* xB    = (short*)(xF + MD);
    short* xIn   = xB + MD;
    short* Q2    = xIn + MD;             // bf16 (B,H,S,DH)
    short* K2    = Q2 + MD;              // bf16 (B,H,S,DH)
    short* VT    = K2 + MD;              // bf16 (B,H,DH,S), sigma-permuted keys
    short* Obf   = VT + MD;              // bf16 attn out (B,S,D)
    short* WTqkv = Obf + MD;
    short* WTo   = WTqkv + 786432;
    short* WTf   = WTo + 262144;
    short* WTin  = WTf + 65536;
    float* cosT2 = (float*)(WTin + 65536);
    float* sinT2 = cosT2 + 16384;
    float* ybuf  = (float*)Q2;           // alias: Q2/K2 dead before final GEMM

    rope_table_k<<<64, 256, 0, stream>>>(cosT2, sinT2);
    cvt_in_k<<<2048, 256, 0, stream>>>(obs, act, xIn);
    wconv_k<<<dim3(16, 18), 256, 0, stream>>>(qW, kW, vW, oW, outW, inW,
                                              WTqkv, WTo, WTf, WTin);

    gemm_k<2><<<dim3(4, 128), 256, 0, stream>>>(xIn, WTin, inb, nullptr, nullptr,
            xF, xB, nullptr, nullptr, nullptr, nullptr, nullptr, nullptr);

    for (int lay = 0; lay < L_; ++lay) {
        gemm_k<0><<<dim3(12, 128), 256, 0, stream>>>(xB, WTqkv + lay * 196608,
                qb + lay * 256, kb + lay * 256, vb + lay * 256,
                nullptr, nullptr, Q2, K2, VT, nullptr, cosT2, sinT2);
        attn_k<<<1024, 512, 0, stream>>>(Q2, K2, VT, Obf);
        gemm_k<1><<<dim3(4, 128), 256, 0, stream>>>(Obf, WTo + lay * 65536,
                ob + lay * 256, nullptr, nullptr, xF, xB,
                nullptr, nullptr, nullptr, nullptr, nullptr, nullptr);
    }

    gemm_k<3><<<dim3(4, 128), 256, 0, stream>>>(xB, WTf, outb, nullptr, nullptr,
            nullptr, nullptr, nullptr, nullptr, nullptr, ybuf, nullptr, nullptr);
    ln_k<<<M_ / 4, 256, 0, stream>>>(ybuf, lng, lnb, outp);
}

// Round 6
// 308.437 us; speedup vs baseline: 1.3029x; 1.0025x over previous
//
#include <hip/hip_runtime.h>
#include <hip/hip_bf16.h>
#include <math.h>

#define B_ 16
#define S_ 1024
#define D_ 256
#define H_ 8
#define L_ 4
#define DH_ 32
#define OBS_ 160
#define ACT_ 96
#define M_ (B_*S_)   // 16384

typedef __attribute__((ext_vector_type(8)))  short short8v;   // 8 bf16
typedef __attribute__((ext_vector_type(4)))  short short4v;   // 4 bf16
typedef __attribute__((ext_vector_type(4)))  float f32x4;
typedef __attribute__((ext_vector_type(4)))  unsigned uint4v;

#define ALPHA_ 0.25507313f   // log2(e)/sqrt(32)

__device__ inline short bf16rne(float x) {
    unsigned u = __builtin_bit_cast(unsigned, x);
    unsigned r = (u + 0x7fffu + ((u >> 16) & 1u)) >> 16;
    return (short)r;
}

#if __has_builtin(__builtin_amdgcn_exp2f)
#define EXP2F(x) __builtin_amdgcn_exp2f(x)
#else
#define EXP2F(x) exp2f(x)
#endif

__device__ inline unsigned cvtpk_bf16(float lo, float hi) {
    unsigned r;
    asm("v_cvt_pk_bf16_f32 %0, %1, %2" : "=v"(r) : "v"(lo), "v"(hi));
    return r;
}

// ------------------------------------------------------------ RoPE table
// [i=0..15][s=0..1023] so epilogues vector-load cos/sin along 4 consecutive s.
__global__ __launch_bounds__(256) void rope_table_k(float* __restrict__ cosT2,
                                                    float* __restrict__ sinT2) {
    int idx = blockIdx.x * 256 + threadIdx.x;   // 16384
    int i = idx >> 10, s = idx & 1023;
    float invf = powf(10000.0f, -(float)(2 * i) / 32.0f);
    float ang = (float)s * invf;
    float sn, cs;
    sincosf(ang, &sn, &cs);
    cosT2[idx] = cs;
    sinT2[idx] = sn;
}

// ------------------------------------------------------------ input concat+cvt
__global__ __launch_bounds__(256) void cvt_in_k(const float* __restrict__ obs,
                                                const float* __restrict__ act,
                                                short* __restrict__ xIn) {
    const int idx = (blockIdx.x * 256 + threadIdx.x) * 8;
    const int row = idx >> 8, col = idx & 255;
    const float* s = (col < OBS_) ? (obs + (size_t)row * OBS_ + col)
                                  : (act + (size_t)row * ACT_ + (col - OBS_));
    const float4 v0 = *(const float4*)s;
    const float4 v1 = *(const float4*)(s + 4);
    short8v o = {bf16rne(v0.x), bf16rne(v0.y), bf16rne(v0.z), bf16rne(v0.w),
                 bf16rne(v1.x), bf16rne(v1.y), bf16rne(v1.z), bf16rne(v1.w)};
    *(short8v*)&xIn[idx] = o;
}

// ------------------------------------------------------------ weight cvt+transpose
__global__ __launch_bounds__(256) void wconv_k(
    const float* __restrict__ qW, const float* __restrict__ kW,
    const float* __restrict__ vW, const float* __restrict__ oW,
    const float* __restrict__ outW, const float* __restrict__ inW,
    short* __restrict__ WTqkv, short* __restrict__ WTo,
    short* __restrict__ WTf, short* __restrict__ WTin)
{
    __shared__ float T[64][65];
    const int z = blockIdx.y;           // 0..17
    const int bx = blockIdx.x;          // 0..15
    const int tr = (bx & 3) * 64, tc = (bx >> 2) * 64;
    const float* src;
    short* dst;
    if (z < 16) {
        int lay = z >> 2, w = z & 3;
        if (w == 0)      { src = qW + lay * 65536; dst = WTqkv + lay * 196608; }
        else if (w == 1) { src = kW + lay * 65536; dst = WTqkv + lay * 196608 + 65536; }
        else if (w == 2) { src = vW + lay * 65536; dst = WTqkv + lay * 196608 + 131072; }
        else             { src = oW + lay * 65536; dst = WTo + lay * 65536; }
    } else if (z == 16) { src = outW; dst = WTf; }
    else                { src = inW;  dst = WTin; }
    const int tid = threadIdx.x;
    #pragma unroll
    for (int it = 0; it < 4; ++it) {
        int r = (tid >> 4) + it * 16, c = (tid & 15) * 4;
        *(float4*)&T[r][c] = *(const float4*)&src[(size_t)(tr + r) * 256 + tc + c];
    }
    __syncthreads();
    #pragma unroll
    for (int it = 0; it < 4; ++it) {
        int n = (tid >> 4) + it * 16, k = (tid & 15) * 4;
        short4v o = {bf16rne(T[k][n]), bf16rne(T[k + 1][n]),
                     bf16rne(T[k + 2][n]), bf16rne(T[k + 3][n])};
        *(short4v*)&dst[(size_t)(tc + n) * 256 + tr + k] = o;
    }
}

// ------------------------------------------------------------ MFMA GEMM
// EPI 0: QKV fused (N=768): Q -> *ALPHA,rope -> (B,H,S,DH); K -> rope ->
//        (B,H,S,DH); V -> (B,H,DH,S) with sigma-permuted key order.
// EPI 1: + residual xF -> xF(f32) + xB(bf16)
// EPI 2: -> xF + xB
// EPI 3: -> yF (f32)
template<int EPI>
__global__ __launch_bounds__(256) void gemm_k(
    const short* __restrict__ A, const short* __restrict__ WT,
    const float* __restrict__ bq, const float* __restrict__ bk,
    const float* __restrict__ bv,
    float* __restrict__ xF, short* __restrict__ xB,
    short* __restrict__ Q2, short* __restrict__ K2, short* __restrict__ VT,
    float* __restrict__ yF,
    const float* __restrict__ cosT2, const float* __restrict__ sinT2)
{
    __shared__ short As[2][128 * 32];
    __shared__ short Bs[2][64 * 32];
    const int tid = threadIdx.x;
    const int l = tid & 63;
    const int wid = tid >> 6, wr = wid >> 1, wc = wid & 1;
    const int bn = blockIdx.x * 64, bm = blockIdx.y * 128;

    const short* aSrc0 = A + (size_t)(bm + (tid >> 2)) * 256 + (tid & 3) * 8;
    const short* aSrc1 = aSrc0 + 64 * 256;
    const short* bSrc  = WT + (size_t)(bn + (tid >> 2)) * 256 + (tid & 3) * 8;

    short8v a0 = *(const short8v*)aSrc0;
    short8v a1 = *(const short8v*)aSrc1;
    short8v b0 = *(const short8v*)bSrc;
    *(short8v*)&As[0][tid * 8]         = a0;
    *(short8v*)&As[0][(tid + 256) * 8] = a1;
    *(short8v*)&Bs[0][tid * 8]         = b0;
    __syncthreads();

    f32x4 acc[4][2];
    #pragma unroll
    for (int i = 0; i < 4; ++i)
        #pragma unroll
        for (int j = 0; j < 2; ++j) acc[i][j] = (f32x4){0.f, 0.f, 0.f, 0.f};

    #pragma unroll
    for (int t = 0; t < 8; ++t) {
        const int cur = t & 1;
        short8v na0, na1, nb;
        if (t < 7) {
            const int k = (t + 1) * 32;
            na0 = *(const short8v*)&aSrc0[k];
            na1 = *(const short8v*)&aSrc1[k];
            nb  = *(const short8v*)&bSrc[k];
        }
        short8v af[4], bf[2];
        #pragma unroll
        for (int i = 0; i < 4; ++i)
            af[i] = *(const short8v*)&As[cur][(wr * 64 + i * 16 + (l & 15)) * 32 + (l >> 4) * 8];
        #pragma unroll
        for (int j = 0; j < 2; ++j)
            bf[j] = *(const short8v*)&Bs[cur][(wc * 32 + j * 16 + (l & 15)) * 32 + (l >> 4) * 8];
        #pragma unroll
        for (int i = 0; i < 4; ++i)
            #pragma unroll
            for (int j = 0; j < 2; ++j)
                acc[i][j] = __builtin_amdgcn_mfma_f32_16x16x32_bf16(af[i], bf[j], acc[i][j], 0, 0, 0);
        if (t < 7) {
            const int nxt = cur ^ 1;
            *(short8v*)&As[nxt][tid * 8]         = na0;
            *(short8v*)&As[nxt][(tid + 256) * 8] = na1;
            *(short8v*)&Bs[nxt][tid * 8]         = nb;
            __syncthreads();
        }
    }

    if (EPI == 0) {
        const int region = bn >> 8;     // 0=Q 1=K 2=V (uniform per block)
        if (region == 2) {
            #pragma unroll
            for (int i = 0; i < 4; ++i) {
                const int m0 = bm + wr * 64 + i * 16 + ((l >> 4) << 2);
                const int bI = m0 >> 10, s0 = m0 & 1023;
                // sigma key-permutation within each 32-block:
                // pos(key): key<16 -> 8*(key>>2)+(key&3); key>=16 -> that +4
                const int w  = s0 & 31;
                const int sp = (s0 & ~31) | ((((w & 15) >> 2) << 3) | ((w >> 4) << 2));
                #pragma unroll
                for (int j = 0; j < 2; ++j) {
                    const int nl = (bn & 255) + wc * 32 + j * 16 + (l & 15);
                    const float bb = bv[nl];
                    const f32x4 v = acc[i][j];
                    const int h = nl >> 5, dhh = nl & 31;
                    short4v o = {bf16rne(v[0] + bb), bf16rne(v[1] + bb),
                                 bf16rne(v[2] + bb), bf16rne(v[3] + bb)};
                    *(short4v*)&VT[((size_t)((bI * 8 + h) * 32 + dhh) << 10) + sp] = o;
                }
            }
        } else {
            // Q/K: bias (+scale) + rope, bounce via LDS -> (B,H,S,DH)
            const float* bias = (region == 0) ? bq : bk;
            __syncthreads();
            short* scr = &As[0][0];   // 128 x 64 bf16, chunk-XOR swizzled
            #pragma unroll
            for (int i = 0; i < 4; ++i) {
                const int tl0 = wr * 64 + i * 16 + ((l >> 4) << 2);
                const int s0r = (bm + tl0) & 1023;
                #pragma unroll
                for (int j = 0; j < 2; ++j) {
                    const int ncl = wc * 32 + j * 16 + (l & 15);
                    const int nl = (bn & 255) + ncl;
                    const float bb = bias[nl];
                    f32x4 v = acc[i][j];
                    v[0] += bb; v[1] += bb; v[2] += bb; v[3] += bb;
                    if (region == 0) { v *= ALPHA_; }
                    const int ir = (nl & 31) >> 1;
                    const f32x4 cs = *(const f32x4*)&cosT2[ir * 1024 + s0r];
                    const f32x4 sn = *(const f32x4*)&sinT2[ir * 1024 + s0r];
                    f32x4 pr;
                    #pragma unroll
                    for (int c = 0; c < 4; ++c) pr[c] = __shfl_xor(v[c], 1);
                    const float sg = (nl & 1) ? 1.f : -1.f;
                    #pragma unroll
                    for (int c = 0; c < 4; ++c)
                        v[c] = v[c] * cs[c] + sg * pr[c] * sn[c];
                    #pragma unroll
                    for (int c = 0; c < 4; ++c) {
                        const int tl = tl0 + c;
                        const int pos = (((ncl >> 3) ^ (tl & 7)) << 3) | (ncl & 7);
                        scr[tl * 64 + pos] = bf16rne(v[c]);
                    }
                }
            }
            __syncthreads();
            const int r = tid >> 1, h2 = tid & 1;
            const int tok = bm + r;
            const int bI = tok >> 10, s0 = tok & 1023;
            const int hh = ((bn & 255) >> 5) + h2;
            short* dst = ((region == 0) ? Q2 : K2)
                         + ((size_t)((bI * 8 + hh) * 1024 + s0)) * 32;
            #pragma unroll
            for (int k = 0; k < 4; ++k) {
                const int pos = ((h2 * 4 + k) ^ (r & 7)) << 3;
                *(uint4*)&dst[k * 8] = *(const uint4*)&scr[r * 64 + pos];
            }
        }
    } else {
        #pragma unroll
        for (int i = 0; i < 4; ++i) {
            const int m0 = bm + wr * 64 + i * 16 + ((l >> 4) << 2);
            #pragma unroll
            for (int j = 0; j < 2; ++j) {
                const int nn = bn + wc * 32 + j * 16 + (l & 15);
                const float bb = bq[nn];
                const f32x4 v = acc[i][j];
                #pragma unroll
                for (int c = 0; c < 4; ++c) {
                    float rr = v[c] + bb;
                    const size_t off = (size_t)(m0 + c) * 256 + nn;
                    if (EPI == 1) rr += xF[off];
                    if (EPI == 3) {
                        yF[off] = rr;
                    } else {
                        xF[off] = rr;
                        xB[off] = bf16rne(rr);
                    }
                }
            }
        }
    }
}

// ------------------------------------------------------------ Attention
// Q2/K2: bf16 (B,H,S,DH) (Q pre-scaled by log2e/sqrt(DH), both rope'd)
// VT:    bf16 (B,H,DH,S), key order sigma-permuted per 32-block
// O:     bf16 (B,S,D)
// Block: 1 head x 256 q (8 waves x 32 q), 16x16x32 MFMA. Each wave owns TWO
// 16-q fragments so the 4 ds_read_b128/step feed 8 MFMAs (halved LDS traffic).
// K/V tiles (32 keys) staged to LDS by waves 0-3 (reg-staged, 1 tile ahead),
// double-buffered, XOR-swizzled chunks. P needs ZERO cross-lane ops: the
// sigma permutation makes the QK C-fragment's key set == PV B-fragment's.
__global__ __launch_bounds__(512, 4) void attn_k(
    const short* __restrict__ Q2, const short* __restrict__ K2,
    const short* __restrict__ VT, short* __restrict__ O)
{
    __shared__ short LB[4096];   // [2 buf][K 32x32 | V 32x32] bf16, 8 KB
    const int tid = threadIdx.x;
    const int l = tid & 63, wid = tid >> 6;
    const int head = blockIdx.x & 127;   // b*8+h; bid%8 = head%8 -> XCD-pinned
    const int qt = blockIdx.x >> 7;      // 0..3
    const int q0w = qt * 256 + wid * 32;
    const int lq = l & 15, g = l >> 4;

    const short* qp = &Q2[((size_t)head * 1024 + q0w + lq) * 32 + g * 8];
    const short8v QfA = *(const short8v*)qp;
    const short8v QfB = *(const short8v*)(qp + 16 * 32);

    // LDS read base: row lq, chunk g, swizzle c' = c ^ ((row>>1)&3)
    const char* rbase = (const char*)LB + lq * 64 + ((g ^ ((lq >> 1) & 3)) << 4);

    // staging (threads 0..255): 0-127 stage K, 128-255 stage V
    const bool stg = (tid < 256);
    const int  sK  = (tid < 128) ? 1 : 0;
    const int  srow = (tid & 127) >> 2;
    const int  sc   = tid & 3;
    const short* gsrc = nullptr;
    int gstep = 0;
    char* wbase = nullptr;
    if (stg) {
        if (sK) { gsrc = K2 + ((size_t)head * 1024 + srow) * 32 + sc * 8; gstep = 1024; }
        else    { gsrc = VT + ((size_t)head * 32 + srow) * 1024 + sc * 8; gstep = 32; }
        wbase = (char*)LB + (sK ? 0 : 2048) + srow * 64 + ((sc ^ ((srow >> 1) & 3)) << 4);
    }

    f32x4 aA0 = {0.f,0.f,0.f,0.f}, aA1 = {0.f,0.f,0.f,0.f};
    f32x4 aB0 = {0.f,0.f,0.f,0.f}, aB1 = {0.f,0.f,0.f,0.f};
    const f32x4 z4 = {0.f, 0.f, 0.f, 0.f};
    float lsA = 0.f, lsB = 0.f;
    short8v r = {};

    if (stg) {
        short8v r0 = *(const short8v*)gsrc; gsrc += gstep;
        r          = *(const short8v*)gsrc; gsrc += gstep;
        *(short8v*)wbase = r0;
    }
    __syncthreads();

#define ATTN_STEP(BUFOFF) do {                                                 \
        short8v Kf0 = *(const short8v*)(rbase + (BUFOFF));                     \
        short8v Kf1 = *(const short8v*)(rbase + (BUFOFF) + 1024);              \
        short8v Vf0 = *(const short8v*)(rbase + (BUFOFF) + 2048);              \
        short8v Vf1 = *(const short8v*)(rbase + (BUFOFF) + 3072);              \
        f32x4 sA0 = __builtin_amdgcn_mfma_f32_16x16x32_bf16(Kf0, QfA, z4, 0,0,0);\
        f32x4 sA1 = __builtin_amdgcn_mfma_f32_16x16x32_bf16(Kf1, QfA, z4, 0,0,0);\
        f32x4 sB0 = __builtin_amdgcn_mfma_f32_16x16x32_bf16(Kf0, QfB, z4, 0,0,0);\
        f32x4 sB1 = __builtin_amdgcn_mfma_f32_16x16x32_bf16(Kf1, QfB, z4, 0,0,0);\
        float pa0 = EXP2F(sA0[0]), pa1 = EXP2F(sA0[1]);                        \
        float pa2 = EXP2F(sA0[2]), pa3 = EXP2F(sA0[3]);                        \
        float pa4 = EXP2F(sA1[0]), pa5 = EXP2F(sA1[1]);                        \
        float pa6 = EXP2F(sA1[2]), pa7 = EXP2F(sA1[3]);                        \
        lsA += ((pa0 + pa1) + (pa2 + pa3)) + ((pa4 + pa5) + (pa6 + pa7));      \
        uint4v pva = {cvtpk_bf16(pa0, pa1), cvtpk_bf16(pa2, pa3),              \
                      cvtpk_bf16(pa4, pa5), cvtpk_bf16(pa6, pa7)};             \
        short8v PfA = __builtin_bit_cast(short8v, pva);                        \
        aA0 = __builtin_amdgcn_mfma_f32_16x16x32_bf16(Vf0, PfA, aA0, 0,0,0);   \
        aA1 = __builtin_amdgcn_mfma_f32_16x16x32_bf16(Vf1, PfA, aA1, 0,0,0);   \
        float pb0 = EXP2F(sB0[0]), pb1 = EXP2F(sB0[1]);                        \
        float pb2 = EXP2F(sB0[2]), pb3 = EXP2F(sB0[3]);                        \
        float pb4 = EXP2F(sB1[0]), pb5 = EXP2F(sB1[1]);                        \
        float pb6 = EXP2F(sB1[2]), pb7 = EXP2F(sB1[3]);                        \
        lsB += ((pb0 + pb1) + (pb2 + pb3)) + ((pb4 + pb5) + (pb6 + pb7));      \
        uint4v pvb = {cvtpk_bf16(pb0, pb1), cvtpk_bf16(pb2, pb3),              \
                      cvtpk_bf16(pb4, pb5), cvtpk_bf16(pb6, pb7)};             \
        short8v PfB = __builtin_bit_cast(short8v, pvb);                        \
        aB0 = __builtin_amdgcn_mfma_f32_16x16x32_bf16(Vf0, PfB, aB0, 0,0,0);   \
        aB1 = __builtin_amdgcn_mfma_f32_16x16x32_bf16(Vf1, PfB, aB1, 0,0,0);   \
    } while (0)

    #pragma unroll 1
    for (int i = 0; i < 15; ++i) {
        if (stg) { *(short8v*)(wbase + 4096) = r;
                   r = *(const short8v*)gsrc; gsrc += gstep; }
        ATTN_STEP(0);
        __syncthreads();
        if (stg) { *(short8v*)wbase = r;
                   r = *(const short8v*)gsrc; gsrc += gstep; }
        ATTN_STEP(4096);
        __syncthreads();
    }
    // t = 30
    if (stg) { *(short8v*)(wbase + 4096) = r; }
    ATTN_STEP(0);
    __syncthreads();
    // t = 31
    ATTN_STEP(4096);
#undef ATTN_STEP

    lsA += __shfl_xor(lsA, 16);
    lsA += __shfl_xor(lsA, 32);
    lsB += __shfl_xor(lsB, 16);
    lsB += __shfl_xor(lsB, 32);
    const float invA = 1.f / lsA;
    const float invB = 1.f / lsB;
    const int bI = head >> 3, hh = head & 7;
    short* op = O + ((size_t)(bI * 1024 + q0w + lq)) * 256 + hh * 32 + g * 4;
    short4v oA0 = {bf16rne(aA0[0] * invA), bf16rne(aA0[1] * invA),
                   bf16rne(aA0[2] * invA), bf16rne(aA0[3] * invA)};
    short4v oA1 = {bf16rne(aA1[0] * invA), bf16rne(aA1[1] * invA),
                   bf16rne(aA1[2] * invA), bf16rne(aA1[3] * invA)};
    *(short4v*)op = oA0;
    *(short4v*)(op + 16) = oA1;
    short* opB = op + 16 * 256;
    short4v oB0 = {bf16rne(aB0[0] * invB), bf16rne(aB0[1] * invB),
                   bf16rne(aB0[2] * invB), bf16rne(aB0[3] * invB)};
    short4v oB1 = {bf16rne(aB1[0] * invB), bf16rne(aB1[1] * invB),
                   bf16rne(aB1[2] * invB), bf16rne(aB1[3] * invB)};
    *(short4v*)opB = oB0;
    *(short4v*)(opB + 16) = oB1;
}

// ------------------------------------------------------------ LayerNorm
__global__ __launch_bounds__(256) void ln_k(
    const float* __restrict__ y, const float* __restrict__ g,
    const float* __restrict__ bta, float* __restrict__ outp)
{
    const int tid = threadIdx.x;
    const int wave = tid >> 6, lane = tid & 63;
    const int row = blockIdx.x * 4 + wave;
    const int col = lane * 4;
    float4 t = *(const float4*)&y[(size_t)row * 256 + col];
    float sum = t.x + t.y + t.z + t.w;
    float ss  = t.x * t.x + t.y * t.y + t.z * t.z + t.w * t.w;
    #pragma unroll
    for (int off = 32; off; off >>= 1) {
        sum += __shfl_xor(sum, off);
        ss  += __shfl_xor(ss, off);
    }
    float mean = sum * (1.f / 256.f);
    float var  = ss * (1.f / 256.f) - mean * mean;
    float rstd = rsqrtf(var + 1e-5f);
    float4 gv = *(const float4*)&g[col];
    float4 bv = *(const float4*)&bta[col];
    float4 o;
    o.x = (t.x - mean) * rstd * gv.x + bv.x;
    o.y = (t.y - mean) * rstd * gv.y + bv.y;
    o.z = (t.z - mean) * rstd * gv.z + bv.z;
    o.w = (t.w - mean) * rstd * gv.w + bv.w;
    float* seq = outp + B_ * D_;
    *(float4*)&seq[(size_t)row * 256 + col] = o;
    if ((row & (S_ - 1)) == S_ - 1)
        *(float4*)&outp[(size_t)(row >> 10) * 256 + col] = o;
}

// ------------------------------------------------------------ launch
extern "C" void kernel_launch(void* const* d_in, const int* in_sizes, int n_in,
                              void* d_out, int out_size, void* d_ws, size_t ws_size,
                              hipStream_t stream)
{
    const float* obs  = (const float*)d_in[0];
    const float* act  = (const float*)d_in[1];
    const float* inW  = (const float*)d_in[2];
    const float* inb  = (const float*)d_in[3];
    const float* qW   = (const float*)d_in[4];
    const float* qb   = (const float*)d_in[5];
    const float* kW   = (const float*)d_in[6];
    const float* kb   = (const float*)d_in[7];
    const float* vW   = (const float*)d_in[8];
    const float* vb   = (const float*)d_in[9];
    const float* oW   = (const float*)d_in[10];
    const float* ob   = (const float*)d_in[11];
    const float* outW = (const float*)d_in[12];
    const float* outb = (const float*)d_in[13];
    const float* lng  = (const float*)d_in[14];
    const float* lnb  = (const float*)d_in[15];
    float* outp = (float*)d_out;

    const size_t MD = (size_t)M_ * D_;
    float* xF    = (float*)d_ws;
    short* xB    = (short*)(xF + MD);
    short* xIn   = xB + MD;
    short* Q2    = xIn + MD;             // bf16 (B,H,S,DH)
    short* K2    = Q2 + MD;              // bf16 (B,H,S,DH)
    short* VT    = K2 + MD;              // bf16 (B,H,DH,S), sigma-permuted keys
    short* Obf   = VT + MD;              // bf16 attn out (B,S,D)
    short* WTqkv = Obf + MD;
    short* WTo   = WTqkv + 786432;
    short* WTf   = WTo + 262144;
    short* WTin  = WTf + 65536;
    float* cosT2 = (float*)(WTin + 65536);
    float* sinT2 = cosT2 + 16384;
    float* ybuf  = (float*)Q2;           // alias: Q2/K2 dead before final GEMM

    rope_table_k<<<64, 256, 0, stream>>>(cosT2, sinT2);
    cvt_in_k<<<2048, 256, 0, stream>>>(obs, act, xIn);
    wconv_k<<<dim3(16, 18), 256, 0, stream>>>(qW, kW, vW, oW, outW, inW,
                                              WTqkv, WTo, WTf, WTin);

    gemm_k<2><<<dim3(4, 128), 256, 0, stream>>>(xIn, WTin, inb, nullptr, nullptr,
            xF, xB, nullptr, nullptr, nullptr, nullptr, nullptr, nullptr);

    for (int lay = 0; lay < L_; ++lay) {
        gemm_k<0><<<dim3(12, 128), 256, 0, stream>>>(xB, WTqkv + lay * 196608,
                qb + lay * 256, kb + lay * 256, vb + lay * 256,
                nullptr, nullptr, Q2, K2, VT, nullptr, cosT2, sinT2);
        attn_k<<<512, 512, 0, stream>>>(Q2, K2, VT, Obf);
        gemm_k<1><<<dim3(4, 128), 256, 0, stream>>>(Obf, WTo + lay * 65536,
                ob + lay * 256, nullptr, nullptr, xF, xB,
                nullptr, nullptr, nullptr, nullptr, nullptr, nullptr);
    }

    gemm_k<3><<<dim3(4, 128), 256, 0, stream>>>(xB, WTf, outb, nullptr, nullptr,
            nullptr, nullptr, nullptr, nullptr, nullptr, ybuf, nullptr, nullptr);
    ln_k<<<M_ / 4, 256, 0, stream>>>(ybuf, lng, lnb, outp);
}